// Round 1
// baseline (151.035 us; speedup 1.0000x reference)
//
#include <hip/hip_runtime.h>
#include <math.h>

#define H_   16
#define NB_  64
#define D_   1024
#define HID_ 64
#define B_   4
#define T_   2048
#define ROWS (B_*T_)    // 8192
#define HNB  (H_*NB_)   // 1024

__device__ __forceinline__ float gelu_exact(float x) {
    return 0.5f * x * (1.0f + erff(x * 0.7071067811865476f));
}
__device__ __forceinline__ float sigmoidf(float x) {
    return 1.0f / (1.0f + expf(-x));
}

// ---------------- Kernel 1: h = gelu(X @ W1 + b1) ----------------
// grid 512, block 256. Each block: 16 rows. LDS-tiled over D in chunks of 128.
__global__ __launch_bounds__(256) void k_gemm1(const float* __restrict__ X,
                                               const float* __restrict__ W1,
                                               const float* __restrict__ b1,
                                               float* __restrict__ hbuf) {
    __shared__ float xs[16][132];   // +4 pad: 4 row-broadcast addrs land on distinct banks
    __shared__ float ws[128][64];
    const int t  = threadIdx.x;
    const int r0 = blockIdx.x * 16;
    const int r  = t >> 4;     // 0..15
    const int j4 = t & 15;     // 0..15 -> j = j4*4..j4*4+3
    float acc0 = 0.f, acc1 = 0.f, acc2 = 0.f, acc3 = 0.f;

    for (int c = 0; c < 8; ++c) {
        __syncthreads();
        // stage x chunk: 16 rows x 128 floats
        #pragma unroll
        for (int q = 0; q < 2; ++q) {
            int s  = q * 256 + t;          // float4 slot 0..511
            int rr = s >> 5;
            int kk = (s & 31) << 2;
            float4 v = *(const float4*)&X[(r0 + rr) * D_ + c * 128 + kk];
            *(float4*)&xs[rr][kk] = v;
        }
        // stage W1 chunk: 128 x 64 (flat contiguous)
        #pragma unroll
        for (int q = 0; q < 8; ++q) {
            int s = q * 256 + t;           // float4 slot 0..2047
            float4 v = *(const float4*)&W1[c * 8192 + s * 4];
            int dd = s >> 4;
            int jj = (s & 15) << 2;
            *(float4*)&ws[dd][jj] = v;
        }
        __syncthreads();
        #pragma unroll 8
        for (int dd = 0; dd < 128; ++dd) {
            float  xv = xs[r][dd];
            float4 w  = *(const float4*)&ws[dd][j4 * 4];
            acc0 = fmaf(xv, w.x, acc0);
            acc1 = fmaf(xv, w.y, acc1);
            acc2 = fmaf(xv, w.z, acc2);
            acc3 = fmaf(xv, w.w, acc3);
        }
    }
    const int j = j4 * 4;
    float4 bb = *(const float4*)&b1[j];
    float4 hv;
    hv.x = gelu_exact(acc0 + bb.x);
    hv.y = gelu_exact(acc1 + bb.y);
    hv.z = gelu_exact(acc2 + bb.z);
    hv.w = gelu_exact(acc3 + bb.w);
    *(float4*)&hbuf[(r0 + r) * HID_ + j] = hv;
}

// ---------------- Kernel 2: gates = sigmoid(h @ W2 + b2) ----------------
// grid 4096 (512 row-blocks x 8 k-chunks), block 256.
__global__ __launch_bounds__(256) void k_gemm2(const float* __restrict__ hbuf,
                                               const float* __restrict__ W2,
                                               const float* __restrict__ b2,
                                               float* __restrict__ gates) {
    __shared__ float w2s[64][128];
    __shared__ float hs[16][64];
    const int t  = threadIdx.x;
    const int rb = blockIdx.x >> 3;
    const int kc = blockIdx.x & 7;
    const int r0 = rb * 16;
    const int k0 = kc * 128;

    // stage W2 chunk 64x128
    #pragma unroll
    for (int q = 0; q < 8; ++q) {
        int s  = q * 256 + t;        // float4 slot 0..2047
        int j  = s >> 5;
        int kk = (s & 31) << 2;
        float4 v = *(const float4*)&W2[j * HNB + k0 + kk];
        *(float4*)&w2s[j][kk] = v;
    }
    // stage h tile 16x64
    {
        int rr = t >> 4;
        int jj = (t & 15) << 2;
        *(float4*)&hs[rr][jj] = *(const float4*)&hbuf[(r0 + rr) * HID_ + jj];
    }
    __syncthreads();

    const int kk2 = t & 63;       // k pair index within chunk
    const int rq  = t >> 6;       // 0..3 -> rows rq*4..rq*4+3
    float a00=0,a01=0,a10=0,a11=0,a20=0,a21=0,a30=0,a31=0;
    #pragma unroll 8
    for (int j = 0; j < 64; ++j) {
        float2 w = *(const float2*)&w2s[j][kk2 * 2];
        float h0 = hs[rq * 4 + 0][j];
        float h1 = hs[rq * 4 + 1][j];
        float h2 = hs[rq * 4 + 2][j];
        float h3 = hs[rq * 4 + 3][j];
        a00 = fmaf(h0, w.x, a00); a01 = fmaf(h0, w.y, a01);
        a10 = fmaf(h1, w.x, a10); a11 = fmaf(h1, w.y, a11);
        a20 = fmaf(h2, w.x, a20); a21 = fmaf(h2, w.y, a21);
        a30 = fmaf(h3, w.x, a30); a31 = fmaf(h3, w.y, a31);
    }
    const int k = k0 + kk2 * 2;
    float2 bb = *(const float2*)&b2[k];
    float2 o;
    int row = r0 + rq * 4;
    o.x = sigmoidf(a00 + bb.x); o.y = sigmoidf(a01 + bb.y);
    *(float2*)&gates[(row + 0) * HNB + k] = o;
    o.x = sigmoidf(a10 + bb.x); o.y = sigmoidf(a11 + bb.y);
    *(float2*)&gates[(row + 1) * HNB + k] = o;
    o.x = sigmoidf(a20 + bb.x); o.y = sigmoidf(a21 + bb.y);
    *(float2*)&gates[(row + 2) * HNB + k] = o;
    o.x = sigmoidf(a30 + bb.x); o.y = sigmoidf(a31 + bb.y);
    *(float2*)&gates[(row + 3) * HNB + k] = o;
}

// ---------------- Kernel 3: the sequential scan ----------------
// grid 64 (b,h), block 64 (nb = lane). One chain per lane, T=2048 steps.
// Per step (ref): s = sigma + Q*th; K = s/(s+R); sigma = s*(1 - g*K)
//   = s*((1-g)s + R)/(s+R).  den = sigma + (Q*th + R) off-chain;
//   p = den - g*s = (1-g)s + R.
#define SCAN_PF 32

#define LOADC(dv, gv, c) { \
    const int bofs_ = base + (c) * SCAN_PF * HNB; \
    _Pragma("unroll") \
    for (int i = 0; i < SCAN_PF; ++i) { \
        dv[i] = delta[bofs_ + i * HNB]; \
        gv[i] = gates[bofs_ + i * HNB]; \
    } }

#define COMPUTEC(dv, gv, c) { \
    const int bofs_ = base + (c) * SCAN_PF * HNB; \
    _Pragma("unroll") \
    for (int i = 0; i < SCAN_PF; ++i) { \
        float t0   = dv[i] * omq;                       /* d*om*sqrt(Q) */ \
        float qthR = fmaf(t0, t0, R);                   /* Q*th + R (off-chain) */ \
        float s    = fmaf(t0, t0, sigma);               /* sigma + Q*th */ \
        float den  = sigma + qthR;                      /* s + R */ \
        float rc   = __builtin_amdgcn_rcpf(den); \
        float p    = fmaf(-gv[i], s, den);              /* (1-g)s + R */ \
        sigma      = (s * p) * rc; \
        sig_out[bofs_ + i * HNB] = sigma; \
    } }

__global__ __launch_bounds__(64) void k_scan(const float* __restrict__ delta,
                                             const float* __restrict__ omega,
                                             const float* __restrict__ log_Q,
                                             const float* __restrict__ log_R,
                                             const float* __restrict__ log_s0,
                                             const float* __restrict__ gates,
                                             float* __restrict__ sig_out) {
    const int lane = threadIdx.x;
    const int b    = blockIdx.x >> 4;
    const int h    = blockIdx.x & 15;
    const int hn   = h * NB_ + lane;

    const float om  = omega[hn];
    const float Q   = expf(log_Q[hn]);
    const float R   = expf(log_R[hn]);
    const float omq = om * sqrtf(Q);
    float sigma     = expf(log_s0[hn]);

    const int base = b * (T_ * HNB) + h * NB_ + lane;

    float dA[SCAN_PF], gA[SCAN_PF], dB[SCAN_PF], gB[SCAN_PF];
    LOADC(dA, gA, 0);
    const int NCH = T_ / SCAN_PF;   // 64
    for (int c = 0; c < NCH; c += 2) {
        LOADC(dB, gB, c + 1);           // c+1 <= NCH-1 always (NCH even)
        COMPUTEC(dA, gA, c);
        if (c + 2 < NCH) LOADC(dA, gA, c + 2);
        COMPUTEC(dB, gB, c + 1);
    }
}

extern "C" void kernel_launch(void* const* d_in, const int* in_sizes, int n_in,
                              void* d_out, int out_size, void* d_ws, size_t ws_size,
                              hipStream_t stream) {
    const float* delta   = (const float*)d_in[0];
    const float* content = (const float*)d_in[1];
    const float* omega   = (const float*)d_in[2];
    const float* log_Q   = (const float*)d_in[3];
    const float* log_R   = (const float*)d_in[4];
    const float* log_s0  = (const float*)d_in[5];
    const float* W1      = (const float*)d_in[6];
    const float* b1      = (const float*)d_in[7];
    const float* W2      = (const float*)d_in[8];
    const float* b2      = (const float*)d_in[9];

    float* sig_out   = (float*)d_out;                       // 8388608 floats
    float* gates_out = sig_out + (size_t)ROWS * HNB;        // next 8388608
    // h scratch (2 MB): prefer workspace; fall back to sigma region (it is
    // fully overwritten by k_scan afterwards, stream-ordered).
    float* hbuf = (ws_size >= (size_t)ROWS * HID_ * sizeof(float))
                      ? (float*)d_ws : sig_out;

    k_gemm1<<<ROWS / 16, 256, 0, stream>>>(content, W1, b1, hbuf);
    k_gemm2<<<(ROWS / 16) * 8, 256, 0, stream>>>(hbuf, W2, b2, gates_out);
    k_scan<<<B_ * H_, 64, 0, stream>>>(delta, omega, log_Q, log_R, log_s0,
                                       gates_out, sig_out);
}

// Round 2
// 144.985 us; speedup vs baseline: 1.0417x; 1.0417x over previous
//
#include <hip/hip_runtime.h>
#include <math.h>

#define H_   16
#define NB_  64
#define D_   1024
#define HID_ 64
#define B_   4
#define T_   2048
#define ROWS (B_*T_)    // 8192
#define HNB  (H_*NB_)   // 1024

__device__ __forceinline__ float gelu_exact(float x) {
    return 0.5f * x * (1.0f + erff(x * 0.7071067811865476f));
}
__device__ __forceinline__ float sigmoidf(float x) {
    return 1.0f / (1.0f + expf(-x));
}

// ---------------- Kernel 1: h = gelu(X @ W1 + b1) ----------------
__global__ __launch_bounds__(256) void k_gemm1(const float* __restrict__ X,
                                               const float* __restrict__ W1,
                                               const float* __restrict__ b1,
                                               float* __restrict__ hbuf) {
    __shared__ float xs[16][132];
    __shared__ float ws[128][64];
    const int t  = threadIdx.x;
    const int r0 = blockIdx.x * 16;
    const int r  = t >> 4;
    const int j4 = t & 15;
    float acc0 = 0.f, acc1 = 0.f, acc2 = 0.f, acc3 = 0.f;

    for (int c = 0; c < 8; ++c) {
        __syncthreads();
        #pragma unroll
        for (int q = 0; q < 2; ++q) {
            int s  = q * 256 + t;
            int rr = s >> 5;
            int kk = (s & 31) << 2;
            float4 v = *(const float4*)&X[(r0 + rr) * D_ + c * 128 + kk];
            *(float4*)&xs[rr][kk] = v;
        }
        #pragma unroll
        for (int q = 0; q < 8; ++q) {
            int s = q * 256 + t;
            float4 v = *(const float4*)&W1[c * 8192 + s * 4];
            int dd = s >> 4;
            int jj = (s & 15) << 2;
            *(float4*)&ws[dd][jj] = v;
        }
        __syncthreads();
        #pragma unroll 8
        for (int dd = 0; dd < 128; ++dd) {
            float  xv = xs[r][dd];
            float4 w  = *(const float4*)&ws[dd][j4 * 4];
            acc0 = fmaf(xv, w.x, acc0);
            acc1 = fmaf(xv, w.y, acc1);
            acc2 = fmaf(xv, w.z, acc2);
            acc3 = fmaf(xv, w.w, acc3);
        }
    }
    const int j = j4 * 4;
    float4 bb = *(const float4*)&b1[j];
    float4 hv;
    hv.x = gelu_exact(acc0 + bb.x);
    hv.y = gelu_exact(acc1 + bb.y);
    hv.z = gelu_exact(acc2 + bb.z);
    hv.w = gelu_exact(acc3 + bb.w);
    *(float4*)&hbuf[(r0 + r) * HID_ + j] = hv;
}

// ---------------- Kernel 2: gates = sigmoid(h @ W2 + b2) ----------------
__global__ __launch_bounds__(256) void k_gemm2(const float* __restrict__ hbuf,
                                               const float* __restrict__ W2,
                                               const float* __restrict__ b2,
                                               float* __restrict__ gates) {
    __shared__ float w2s[64][128];
    __shared__ float hs[16][64];
    const int t  = threadIdx.x;
    const int rb = blockIdx.x >> 3;
    const int kc = blockIdx.x & 7;
    const int r0 = rb * 16;
    const int k0 = kc * 128;

    #pragma unroll
    for (int q = 0; q < 8; ++q) {
        int s  = q * 256 + t;
        int j  = s >> 5;
        int kk = (s & 31) << 2;
        float4 v = *(const float4*)&W2[j * HNB + k0 + kk];
        *(float4*)&w2s[j][kk] = v;
    }
    {
        int rr = t >> 4;
        int jj = (t & 15) << 2;
        *(float4*)&hs[rr][jj] = *(const float4*)&hbuf[(r0 + rr) * HID_ + jj];
    }
    __syncthreads();

    const int kk2 = t & 63;
    const int rq  = t >> 6;
    float a00=0,a01=0,a10=0,a11=0,a20=0,a21=0,a30=0,a31=0;
    #pragma unroll 8
    for (int j = 0; j < 64; ++j) {
        float2 w = *(const float2*)&w2s[j][kk2 * 2];
        float h0 = hs[rq * 4 + 0][j];
        float h1 = hs[rq * 4 + 1][j];
        float h2 = hs[rq * 4 + 2][j];
        float h3 = hs[rq * 4 + 3][j];
        a00 = fmaf(h0, w.x, a00); a01 = fmaf(h0, w.y, a01);
        a10 = fmaf(h1, w.x, a10); a11 = fmaf(h1, w.y, a11);
        a20 = fmaf(h2, w.x, a20); a21 = fmaf(h2, w.y, a21);
        a30 = fmaf(h3, w.x, a30); a31 = fmaf(h3, w.y, a31);
    }
    const int k = k0 + kk2 * 2;
    float2 bb = *(const float2*)&b2[k];
    float2 o;
    int row = r0 + rq * 4;
    o.x = sigmoidf(a00 + bb.x); o.y = sigmoidf(a01 + bb.y);
    *(float2*)&gates[(row + 0) * HNB + k] = o;
    o.x = sigmoidf(a10 + bb.x); o.y = sigmoidf(a11 + bb.y);
    *(float2*)&gates[(row + 1) * HNB + k] = o;
    o.x = sigmoidf(a20 + bb.x); o.y = sigmoidf(a21 + bb.y);
    *(float2*)&gates[(row + 2) * HNB + k] = o;
    o.x = sigmoidf(a30 + bb.x); o.y = sigmoidf(a31 + bb.y);
    *(float2*)&gates[(row + 3) * HNB + k] = o;
}

// ---------------- Kernel T: fused square+scale+transpose ----------------
// thsqT[(b*16+h)*64+nb][t] = Q*(delta*omega)^2 ; gatesT same layout (copy).
// grid: (b*16+h)*32 + t_tile  (2048 blocks), block 256.
__global__ __launch_bounds__(256) void k_transpose(const float* __restrict__ delta,
                                                   const float* __restrict__ gates,
                                                   const float* __restrict__ omega,
                                                   const float* __restrict__ log_Q,
                                                   float* __restrict__ thsqT,
                                                   float* __restrict__ gatesT) {
    const int tile = blockIdx.x;
    const int tt = tile & 31;
    const int bh = tile >> 5;     // 0..63
    const int h  = bh & 15;
    const int b  = bh >> 4;
    const int t0 = tt * 64;
    __shared__ float ld[64][66];  // pad 66: col reads 2-way conflict (free)
    __shared__ float lg[64][66];
    const int tid = threadIdx.x;

    #pragma unroll
    for (int q = 0; q < 4; ++q) {
        int idx = q * 256 + tid;
        int row = idx >> 4;        // t offset 0..63
        int c4  = idx & 15;        // nb float4 idx
        size_t src = ((size_t)(b * T_ + t0 + row)) * HNB + h * NB_ + c4 * 4;
        float4 v = *(const float4*)&delta[src];
        ld[row][c4*4+0] = v.x; ld[row][c4*4+1] = v.y;
        ld[row][c4*4+2] = v.z; ld[row][c4*4+3] = v.w;
        float4 g = *(const float4*)&gates[src];
        lg[row][c4*4+0] = g.x; lg[row][c4*4+1] = g.y;
        lg[row][c4*4+2] = g.z; lg[row][c4*4+3] = g.w;
    }
    __syncthreads();
    #pragma unroll
    for (int q = 0; q < 4; ++q) {
        int idx = q * 256 + tid;
        int onb = idx >> 4;        // 0..63
        int ot4 = idx & 15;        // t float4 idx
        float om = omega[h * NB_ + onb];
        float Qv = expf(log_Q[h * NB_ + onb]);
        float sc = Qv * om * om;
        float d0 = ld[ot4*4+0][onb], d1 = ld[ot4*4+1][onb],
              d2 = ld[ot4*4+2][onb], d3 = ld[ot4*4+3][onb];
        float4 o;
        o.x = sc * d0 * d0; o.y = sc * d1 * d1;
        o.z = sc * d2 * d2; o.w = sc * d3 * d3;
        float4 og;
        og.x = lg[ot4*4+0][onb]; og.y = lg[ot4*4+1][onb];
        og.z = lg[ot4*4+2][onb]; og.w = lg[ot4*4+3][onb];
        size_t obase = ((size_t)(bh * NB_ + onb)) * T_ + t0 + ot4 * 4;
        *(float4*)&thsqT[obase] = o;
        *(float4*)&gatesT[obase] = og;
    }
}

// ---------------- Kernel 3 (fast): scan over transposed inputs ----------------
// grid 64 (b,h), block 64 (nb=lane). Lane-local contiguous chains.
#define SC_F4 8           // float4 per chunk = 32 steps

#define T_LOAD(thv, gv, c) { \
    _Pragma("unroll") \
    for (int i = 0; i < SC_F4; ++i) { \
        thv[i] = pth[(c) * SC_F4 + i]; \
        gv[i]  = pg [(c) * SC_F4 + i]; \
    } }

#define T_STEP(a, g, tidx) { \
    float aR  = a + R; \
    float s   = sigma + a; \
    float den = sigma + aR; \
    float rc  = __builtin_amdgcn_rcpf(den); \
    float p   = fmaf(-(g), s, den); \
    sigma     = (s * p) * rc; \
    out[(size_t)(tbase + (tidx)) * HNB] = sigma; }

#define T_COMP(thv, gv, c) { \
    const int tbase = (c) * 32; \
    _Pragma("unroll") \
    for (int i = 0; i < SC_F4; ++i) { \
        T_STEP(thv[i].x, gv[i].x, i*4+0); \
        T_STEP(thv[i].y, gv[i].y, i*4+1); \
        T_STEP(thv[i].z, gv[i].z, i*4+2); \
        T_STEP(thv[i].w, gv[i].w, i*4+3); \
    } }

__global__ __launch_bounds__(64) void k_scan_t(const float* __restrict__ thsqT,
                                               const float* __restrict__ gatesT,
                                               const float* __restrict__ log_R,
                                               const float* __restrict__ log_s0,
                                               float* __restrict__ sig_out) {
    const int lane = threadIdx.x;
    const int bh   = blockIdx.x;
    const int b    = bh >> 4;
    const int h    = bh & 15;
    const int hn   = h * NB_ + lane;

    const float R = expf(log_R[hn]);
    float sigma   = expf(log_s0[hn]);

    const float4* pth = (const float4*)&thsqT[(size_t)(bh * NB_ + lane) * T_];
    const float4* pg  = (const float4*)&gatesT[(size_t)(bh * NB_ + lane) * T_];
    float* out = sig_out + (size_t)b * T_ * HNB + hn;

    float4 thA[SC_F4], gA[SC_F4], thB[SC_F4], gB[SC_F4];
    T_LOAD(thA, gA, 0);
    const int NCH = T_ / 32;   // 64
    for (int c = 0; c < NCH; c += 2) {
        T_LOAD(thB, gB, c + 1);
        T_COMP(thA, gA, c);
        if (c + 2 < NCH) T_LOAD(thA, gA, c + 2);
        T_COMP(thB, gB, c + 1);
    }
}

// ---------------- Fallback scan (non-transposed), from R0 ----------------
#define SCAN_PF 32
#define LOADC(dv, gv, c) { \
    const int bofs_ = base + (c) * SCAN_PF * HNB; \
    _Pragma("unroll") \
    for (int i = 0; i < SCAN_PF; ++i) { \
        dv[i] = delta[bofs_ + i * HNB]; \
        gv[i] = gates[bofs_ + i * HNB]; \
    } }
#define COMPUTEC(dv, gv, c) { \
    const int bofs_ = base + (c) * SCAN_PF * HNB; \
    _Pragma("unroll") \
    for (int i = 0; i < SCAN_PF; ++i) { \
        float t0   = dv[i] * omq; \
        float qthR = fmaf(t0, t0, R); \
        float s    = fmaf(t0, t0, sigma); \
        float den  = sigma + qthR; \
        float rc   = __builtin_amdgcn_rcpf(den); \
        float p    = fmaf(-gv[i], s, den); \
        sigma      = (s * p) * rc; \
        sig_out[bofs_ + i * HNB] = sigma; \
    } }

__global__ __launch_bounds__(64) void k_scan(const float* __restrict__ delta,
                                             const float* __restrict__ omega,
                                             const float* __restrict__ log_Q,
                                             const float* __restrict__ log_R,
                                             const float* __restrict__ log_s0,
                                             const float* __restrict__ gates,
                                             float* __restrict__ sig_out) {
    const int lane = threadIdx.x;
    const int b    = blockIdx.x >> 4;
    const int h    = blockIdx.x & 15;
    const int hn   = h * NB_ + lane;

    const float om  = omega[hn];
    const float Q   = expf(log_Q[hn]);
    const float R   = expf(log_R[hn]);
    const float omq = om * sqrtf(Q);
    float sigma     = expf(log_s0[hn]);

    const int base = b * (T_ * HNB) + h * NB_ + lane;

    float dA[SCAN_PF], gA[SCAN_PF], dB[SCAN_PF], gB[SCAN_PF];
    LOADC(dA, gA, 0);
    const int NCH = T_ / SCAN_PF;
    for (int c = 0; c < NCH; c += 2) {
        LOADC(dB, gB, c + 1);
        COMPUTEC(dA, gA, c);
        if (c + 2 < NCH) LOADC(dA, gA, c + 2);
        COMPUTEC(dB, gB, c + 1);
    }
}

extern "C" void kernel_launch(void* const* d_in, const int* in_sizes, int n_in,
                              void* d_out, int out_size, void* d_ws, size_t ws_size,
                              hipStream_t stream) {
    const float* delta   = (const float*)d_in[0];
    const float* content = (const float*)d_in[1];
    const float* omega   = (const float*)d_in[2];
    const float* log_Q   = (const float*)d_in[3];
    const float* log_R   = (const float*)d_in[4];
    const float* log_s0  = (const float*)d_in[5];
    const float* W1      = (const float*)d_in[6];
    const float* b1      = (const float*)d_in[7];
    const float* W2      = (const float*)d_in[8];
    const float* b2      = (const float*)d_in[9];

    float* sig_out   = (float*)d_out;                    // 8388608 floats
    float* gates_out = sig_out + (size_t)ROWS * HNB;     // next 8388608

    const size_t n_sig   = (size_t)ROWS * HNB;           // 8388608
    const size_t n_h     = (size_t)ROWS * HID_;          // 524288
    const size_t need_fast = (2 * n_sig + n_h) * sizeof(float);  // ~69 MB

    if (ws_size >= need_fast) {
        float* thsqT  = (float*)d_ws;
        float* gatesT = thsqT + n_sig;
        float* hbuf   = gatesT + n_sig;
        k_gemm1<<<ROWS / 16, 256, 0, stream>>>(content, W1, b1, hbuf);
        k_gemm2<<<(ROWS / 16) * 8, 256, 0, stream>>>(hbuf, W2, b2, gates_out);
        k_transpose<<<B_ * H_ * 32, 256, 0, stream>>>(delta, gates_out, omega,
                                                      log_Q, thsqT, gatesT);
        k_scan_t<<<B_ * H_, 64, 0, stream>>>(thsqT, gatesT, log_R, log_s0, sig_out);
    } else {
        float* hbuf = (ws_size >= n_h * sizeof(float)) ? (float*)d_ws : sig_out;
        k_gemm1<<<ROWS / 16, 256, 0, stream>>>(content, W1, b1, hbuf);
        k_gemm2<<<(ROWS / 16) * 8, 256, 0, stream>>>(hbuf, W2, b2, gates_out);
        k_scan<<<B_ * H_, 64, 0, stream>>>(delta, omega, log_Q, log_R, log_s0,
                                           gates_out, sig_out);
    }
}